// Round 6
// baseline (89.373 us; speedup 1.0000x reference)
//
#include <hip/hip_runtime.h>
#include <math.h>

#define NBOX 2048
#define NBATCH 8
#define MAX_INST 100
#define MIN_CONF 0.15f
#define NMS_THR 0.3f
#define BLOCK 512
#define NWAVE 8
#define WIN 256
#define NCH 4          // WIN / 64

typedef unsigned long long ull;

// Decode one box exactly in the reference's f32 op order (no FMA contraction).
__device__ inline float4 decode_box(float4 r, float4 d,
                                    float wy1, float wx1, float wy2, float wx2) {
    float h  = __fsub_rn(r.z, r.x);
    float w  = __fsub_rn(r.w, r.y);
    float dy = __fmul_rn(d.x, 0.1f);
    float dx = __fmul_rn(d.y, 0.1f);
    float dh = __fmul_rn(d.z, 0.2f);
    float dw = __fmul_rn(d.w, 0.2f);
    float cy = __fadd_rn(__fadd_rn(r.x, __fmul_rn(0.5f, h)), __fmul_rn(dy, h));
    float cx = __fadd_rn(__fadd_rn(r.y, __fmul_rn(0.5f, w)), __fmul_rn(dx, w));
    float h2 = __fmul_rn(h, expf(dh));
    float w2 = __fmul_rn(w, expf(dw));
    float y1 = __fsub_rn(cy, __fmul_rn(0.5f, h2));
    float x1 = __fsub_rn(cx, __fmul_rn(0.5f, w2));
    float y2 = __fadd_rn(y1, h2);
    float x2 = __fadd_rn(x1, w2);
    float4 b;
    b.x = fminf(fmaxf(y1, wy1), wy2);
    b.y = fminf(fmaxf(x1, wx1), wx2);
    b.z = fminf(fmaxf(y2, wy1), wy2);
    b.w = fminf(fmaxf(x2, wx1), wx2);
    return b;
}

// Exact reference op order (operand-symmetric => iou(a,b)==iou(b,a)).
__device__ inline float iou_pair(float4 a, float4 b) {
    float areaA = __fmul_rn(__fsub_rn(a.z, a.x), __fsub_rn(a.w, a.y));
    float areaB = __fmul_rn(__fsub_rn(b.z, b.x), __fsub_rn(b.w, b.y));
    float iy1 = fmaxf(a.x, b.x);
    float ix1 = fmaxf(a.y, b.y);
    float iy2 = fminf(a.z, b.z);
    float ix2 = fminf(a.w, b.w);
    float ih = fmaxf(__fsub_rn(iy2, iy1), 0.0f);
    float iw = fmaxf(__fsub_rn(ix2, ix1), 0.0f);
    float inter = __fmul_rn(ih, iw);
    float uni = __fadd_rn(__fsub_rn(__fadd_rn(areaA, areaB), inter), 1e-8f);
    return __fdiv_rn(inter, uni);
}

__device__ inline ull shfl_xor64(ull x, int d) {
    unsigned lo = (unsigned)x, hi = (unsigned)(x >> 32);
    lo = __shfl_xor(lo, d);
    hi = __shfl_xor(hi, d);
    return ((ull)hi << 32) | lo;
}

__device__ inline void cmpsel(ull& a, ull& b, bool takeMinA) {
    ull mn = a < b ? a : b;
    ull mx = a < b ? b : a;
    a = takeMinA ? mn : mx;
    b = takeMinA ? mx : mn;
}

__global__ __launch_bounds__(BLOCK)
void detect_refine_kernel(const float* __restrict__ rois,
                          const float* __restrict__ scores_in,
                          const float* __restrict__ deltas,
                          const float* __restrict__ window,
                          float* __restrict__ out) {
    const int b    = blockIdx.x;
    const int tid  = threadIdx.x;
    const int lane = tid & 63;
    const int wid  = tid >> 6;

    __shared__ ull    keys[NBOX];          // 16 KiB  (~score_bits)<<32 | orig_idx
    __shared__ float4 sboxes[NBOX];        // 32 KiB  decoded boxes, by ORIGINAL idx
    __shared__ float  sscores[NBOX];       //  8 KiB  by ORIGINAL idx
    __shared__ float4 cbox[WIN];           //  4 KiB  dense window candidates
    __shared__ float  cscore[WIN];         //  1 KiB
    __shared__ ull    s_masks[WIN][NCH];   //  8 KiB  in-window IoU>thr rows
    __shared__ ull    s_aliveInit[NCH];
    __shared__ ull    s_dead2[NCH][2];
    __shared__ float4 s_keptbox[MAX_INST]; //  1.6 KiB
    __shared__ int    s_kslot[MAX_INST];
    __shared__ int    s_m;

    const float wy1 = window[b * 4 + 0];
    const float wx1 = window[b * 4 + 1];
    const float wy2 = window[b * 4 + 2];
    const float wx2 = window[b * 4 + 3];

    float* outb = out + (size_t)b * MAX_INST * 5;
    for (int i = tid; i < MAX_INST * 5; i += BLOCK) outb[i] = 0.0f;

    // ---- Phase A1: coalesced load + decode, stored by ORIGINAL index ----
    for (int e = tid; e < NBOX; e += BLOCK) {
        float4 r = ((const float4*)rois)[b * NBOX + e];
        float4 d = ((const float4*)deltas)[b * NBOX + e];
        float  s = scores_in[b * NBOX + e];
        sboxes[e]  = decode_box(r, d, wy1, wx1, wy2, wx2);
        sscores[e] = s;
    }

    // ---- Phase A2: sort keys in registers (4 consecutive elements/thread) ----
    const int e0 = tid * 4;
    ull v[4];
    {
        float4 sc = ((const float4*)(scores_in + (size_t)b * NBOX))[tid];
        float s4[4] = {sc.x, sc.y, sc.z, sc.w};
#pragma unroll
        for (int s = 0; s < 4; ++s) {
            unsigned u = __float_as_uint(s4[s]);
            u = (u & 0x80000000u) ? ~u : (u | 0x80000000u);
            v[s] = ((ull)(~u) << 32) | (unsigned)(e0 + s);
        }
    }

    // ---- Phase B: bitonic sort ascending (= score descending, stable) ----
    for (unsigned k = 2; k <= NBOX; k <<= 1) {
        if (k >= 512) {
#pragma unroll
            for (int s = 0; s < 4; ++s) keys[e0 + s] = v[s];
            __syncthreads();
            for (unsigned j = k >> 1; j >= 256; j >>= 1) {
                for (int t = tid; t < NBOX / 2; t += BLOCK) {
                    int i = 2 * t - (t & (j - 1));
                    int p = i | j;
                    bool up = ((i & k) == 0);
                    ull a = keys[i], c = keys[p];
                    bool sw = up ? (a > c) : (a < c);
                    if (sw) { keys[i] = c; keys[p] = a; }
                }
                __syncthreads();
            }
#pragma unroll
            for (int s = 0; s < 4; ++s) v[s] = keys[e0 + s];
        }
        unsigned jstart = ((k >> 1) > 128u) ? 128u : (k >> 1);
        for (unsigned j = jstart; j >= 4; j >>= 1) {
            int d = (int)(j >> 2);
#pragma unroll
            for (int s = 0; s < 4; ++s) {
                ull p = shfl_xor64(v[s], d);
                int e = e0 + s;
                bool takeMin = (((e & j) == 0) == ((e & k) == 0));
                v[s] = takeMin ? (v[s] < p ? v[s] : p) : (v[s] > p ? v[s] : p);
            }
        }
        if (k >= 4) {   // j == 2
            bool up = ((e0 & k) == 0);
            cmpsel(v[0], v[2], up);
            cmpsel(v[1], v[3], up);
        }
        {               // j == 1
            bool upA = ((e0 & k) == 0);
            bool upB = (((e0 + 2) & k) == 0);
            cmpsel(v[0], v[1], upA);
            cmpsel(v[2], v[3], upB);
        }
    }
#pragma unroll
    for (int s = 0; s < 4; ++s) keys[e0 + s] = v[s];
    __syncthreads();

    // ---- Phase C: super-window (256-wide) greedy NMS ----
    int count = 0;
    for (int base = 0; base < NBOX && count < MAX_INST; base += WIN) {
        // C1: dense copy of window candidates + validity ballots (waves 0-3).
        if (tid < WIN) {
            int oi = (int)(keys[base + tid] & 0xFFFFFFFFull);
            float4 bb = sboxes[oi];
            float  ss = sscores[oi];
            cbox[tid]   = bb;
            cscore[tid] = ss;
            ull bal = __ballot(ss >= MIN_CONF);
            if (lane == 0) s_aliveInit[wid] = bal;
        }
        __syncthreads();

        // C2a: dead-check vs previously kept (2 waves per 64-candidate group).
        {
            const int g = wid >> 1, sub = wid & 1;
            float4 myc = cbox[(g << 6) + lane];
            bool deadp = false;
            for (int k = sub; k < count; k += 2)
                deadp |= (iou_pair(s_keptbox[k], myc) > NMS_THR);
            ull bal = __ballot(deadp);
            if (lane == 0) s_dead2[g][sub] = bal;
        }
        // C2b: in-window mask rows (wave w owns rows w, w+8, ...).
        for (int i = wid; i < WIN; i += NWAVE) {
            float4 bi = cbox[i];
#pragma unroll
            for (int q = 0; q < NCH; ++q) {
                ull mrow = 0;
                if ((q << 6) + 63 > i) {          // chunk has cols > i
                    int col = (q << 6) + lane;
                    bool pred = (col > i) && (iou_pair(bi, cbox[col]) > NMS_THR);
                    mrow = __ballot(pred);
                }
                if (lane == 0) s_masks[i][q] = mrow;
            }
        }
        __syncthreads();

        // C3: greedy chain over 256-bit alive vector (wave 0).
        if (wid == 0) {
            ull aliveL = 0;
            if (lane < NCH)
                aliveL = s_aliveInit[lane] & ~(s_dead2[lane][0] | s_dead2[lane][1]);
            int m = 0;
            const int maxm = MAX_INST - count;
            while (m < maxm) {
                int pos = (lane < NCH && aliveL)
                            ? ((lane << 6) + __builtin_ctzll(aliveL)) : WIN;
                pos = min(pos, __shfl_xor(pos, 1));
                pos = min(pos, __shfl_xor(pos, 2));
                pos = __shfl(pos, 0);
                if (pos >= WIN) break;
                if (lane == 0) s_kslot[m] = pos;
                ++m;
                if (lane < NCH) {
                    ull row = s_masks[pos][lane];
                    if (lane == (pos >> 6)) row |= (1ull << (pos & 63));
                    aliveL &= ~row;
                }
            }
            if (lane == 0) s_m = m;
        }
        __syncthreads();

        // C4: parallel output write + kept-list append.
        const int m = s_m;
        if (tid < m) {
            int slot = s_kslot[tid];
            float4 bb = cbox[slot];
            s_keptbox[count + tid] = bb;
            float* o = outb + (size_t)(count + tid) * 5;
            o[0] = bb.x; o[1] = bb.y; o[2] = bb.z; o[3] = bb.w;
            o[4] = cscore[slot];
        }
        count += m;
        __syncthreads();   // keptbox/cbox reuse safe for next window
    }
}

extern "C" void kernel_launch(void* const* d_in, const int* in_sizes, int n_in,
                              void* d_out, int out_size, void* d_ws, size_t ws_size,
                              hipStream_t stream) {
    const float* rois    = (const float*)d_in[0];
    const float* scores  = (const float*)d_in[1];
    const float* deltas  = (const float*)d_in[2];
    const float* window  = (const float*)d_in[3];
    float* out = (float*)d_out;
    detect_refine_kernel<<<NBATCH, BLOCK, 0, stream>>>(rois, scores, deltas, window, out);
}

// Round 7
// 47.049 us; speedup vs baseline: 1.8996x; 1.8996x over previous
//
#include <hip/hip_runtime.h>
#include <math.h>

#define NBOX 2048
#define NBATCH 8
#define MAX_INST 100
#define MIN_CONF 0.15f
#define NMS_THR 0.3f
#define BLOCK 512
#define NWAVE 8

typedef unsigned long long ull;

// Decode one box exactly in the reference's f32 op order (no FMA contraction).
__device__ inline float4 decode_box(float4 r, float4 d,
                                    float wy1, float wx1, float wy2, float wx2) {
    float h  = __fsub_rn(r.z, r.x);
    float w  = __fsub_rn(r.w, r.y);
    float dy = __fmul_rn(d.x, 0.1f);
    float dx = __fmul_rn(d.y, 0.1f);
    float dh = __fmul_rn(d.z, 0.2f);
    float dw = __fmul_rn(d.w, 0.2f);
    float cy = __fadd_rn(__fadd_rn(r.x, __fmul_rn(0.5f, h)), __fmul_rn(dy, h));
    float cx = __fadd_rn(__fadd_rn(r.y, __fmul_rn(0.5f, w)), __fmul_rn(dx, w));
    float h2 = __fmul_rn(h, expf(dh));
    float w2 = __fmul_rn(w, expf(dw));
    float y1 = __fsub_rn(cy, __fmul_rn(0.5f, h2));
    float x1 = __fsub_rn(cx, __fmul_rn(0.5f, w2));
    float y2 = __fadd_rn(y1, h2);
    float x2 = __fadd_rn(x1, w2);
    float4 b;
    b.x = fminf(fmaxf(y1, wy1), wy2);
    b.y = fminf(fmaxf(x1, wx1), wx2);
    b.z = fminf(fmaxf(y2, wy1), wy2);
    b.w = fminf(fmaxf(x2, wx1), wx2);
    return b;
}

// Exact reference op order (operand-symmetric => iou(a,b)==iou(b,a)).
__device__ inline float iou_pair(float4 a, float4 b) {
    float areaA = __fmul_rn(__fsub_rn(a.z, a.x), __fsub_rn(a.w, a.y));
    float areaB = __fmul_rn(__fsub_rn(b.z, b.x), __fsub_rn(b.w, b.y));
    float iy1 = fmaxf(a.x, b.x);
    float ix1 = fmaxf(a.y, b.y);
    float iy2 = fminf(a.z, b.z);
    float ix2 = fminf(a.w, b.w);
    float ih = fmaxf(__fsub_rn(iy2, iy1), 0.0f);
    float iw = fmaxf(__fsub_rn(ix2, ix1), 0.0f);
    float inter = __fmul_rn(ih, iw);
    float uni = __fadd_rn(__fsub_rn(__fadd_rn(areaA, areaB), inter), 1e-8f);
    return __fdiv_rn(inter, uni);
}

__device__ inline ull shfl_xor64(ull x, int d) {
    unsigned lo = (unsigned)x, hi = (unsigned)(x >> 32);
    lo = __shfl_xor(lo, d);
    hi = __shfl_xor(hi, d);
    return ((ull)hi << 32) | lo;
}

__device__ inline void cmpsel(ull& a, ull& b, bool takeMinA) {
    ull mn = a < b ? a : b;
    ull mx = a < b ? b : a;
    a = takeMinA ? mn : mx;
    b = takeMinA ? mx : mn;
}

__global__ __launch_bounds__(BLOCK)
void detect_refine_kernel(const float* __restrict__ rois,
                          const float* __restrict__ scores_in,
                          const float* __restrict__ deltas,
                          const float* __restrict__ window,
                          float* __restrict__ out) {
    const int b    = blockIdx.x;
    const int tid  = threadIdx.x;
    const int lane = tid & 63;
    const int wid  = tid >> 6;

    __shared__ ull    keys[NBOX];           // 16 KiB  (~score_bits)<<32 | orig_idx
    __shared__ float4 sboxes[NBOX];         // 32 KiB  decoded boxes, ORIGINAL idx
    __shared__ float  sscores[NBOX];        //  8 KiB  ORIGINAL idx
    __shared__ ull    dead8[NWAVE];
    __shared__ float4 s_keptbox[MAX_INST];  //  1.6 KiB
    __shared__ float  s_keptscore[MAX_INST];
    __shared__ int    s_m;

    const float wy1 = window[b * 4 + 0];
    const float wx1 = window[b * 4 + 1];
    const float wy2 = window[b * 4 + 2];
    const float wx2 = window[b * 4 + 3];

    float* outb = out + (size_t)b * MAX_INST * 5;

    // ---- Phase A1: coalesced load + decode, stored by ORIGINAL index ----
    for (int e = tid; e < NBOX; e += BLOCK) {
        float4 r = ((const float4*)rois)[b * NBOX + e];
        float4 d = ((const float4*)deltas)[b * NBOX + e];
        float  s = scores_in[b * NBOX + e];
        sboxes[e]  = decode_box(r, d, wy1, wx1, wy2, wx2);
        sscores[e] = s;
    }

    // ---- Phase A2: sort keys in registers (4 consecutive elements/thread) ----
    const int e0 = tid * 4;
    ull v[4];
    {
        float4 sc = ((const float4*)(scores_in + (size_t)b * NBOX))[tid];
        float s4[4] = {sc.x, sc.y, sc.z, sc.w};
#pragma unroll
        for (int s = 0; s < 4; ++s) {
            unsigned u = __float_as_uint(s4[s]);
            u = (u & 0x80000000u) ? ~u : (u | 0x80000000u);
            v[s] = ((ull)(~u) << 32) | (unsigned)(e0 + s);
        }
    }

    // ---- Phase B: bitonic sort ascending (= score descending, stable) ----
    for (unsigned k = 2; k <= NBOX; k <<= 1) {
        if (k >= 512) {
#pragma unroll
            for (int s = 0; s < 4; ++s) keys[e0 + s] = v[s];
            __syncthreads();
            for (unsigned j = k >> 1; j >= 256; j >>= 1) {
                for (int t = tid; t < NBOX / 2; t += BLOCK) {
                    int i = 2 * t - (t & (j - 1));
                    int p = i | j;
                    bool up = ((i & k) == 0);
                    ull a = keys[i], c = keys[p];
                    bool sw = up ? (a > c) : (a < c);
                    if (sw) { keys[i] = c; keys[p] = a; }
                }
                __syncthreads();
            }
#pragma unroll
            for (int s = 0; s < 4; ++s) v[s] = keys[e0 + s];
        }
        unsigned jstart = ((k >> 1) > 128u) ? 128u : (k >> 1);
        for (unsigned j = jstart; j >= 4; j >>= 1) {
            int d = (int)(j >> 2);
#pragma unroll
            for (int s = 0; s < 4; ++s) {
                ull p = shfl_xor64(v[s], d);
                int e = e0 + s;
                bool takeMin = (((e & j) == 0) == ((e & k) == 0));
                v[s] = takeMin ? (v[s] < p ? v[s] : p) : (v[s] > p ? v[s] : p);
            }
        }
        if (k >= 4) {   // j == 2
            bool up = ((e0 & k) == 0);
            cmpsel(v[0], v[2], up);
            cmpsel(v[1], v[3], up);
        }
        {               // j == 1
            bool upA = ((e0 & k) == 0);
            bool upB = (((e0 + 2) & k) == 0);
            cmpsel(v[0], v[1], upA);
            cmpsel(v[2], v[3], upB);
        }
    }
#pragma unroll
    for (int s = 0; s < 4; ++s) keys[e0 + s] = v[s];
    __syncthreads();

    // ---- Phase C: window-batched greedy NMS, maskless register chain ----
    int count = 0;
    for (int base = 0; base < NBOX && count < MAX_INST; base += 64) {
        // Candidate for this lane (same in every wave).
        int    oi = (int)(keys[base + lane] & 0xFFFFFFFFull);
        float4 bj = sboxes[oi];
        float  sj = sscores[oi];

        // Dead-check vs previously kept boxes, strided across the 8 waves.
        bool deadp = (sj < MIN_CONF);
        for (int k = wid; k < count; k += NWAVE)
            deadp |= (iou_pair(s_keptbox[k], bj) > NMS_THR);
        ull bal = __ballot(deadp);
        if (lane == 0) dead8[wid] = bal;
        __syncthreads();

        // Wave 0: maskless greedy chain — broadcast keep, 1 IoU per lane.
        if (wid == 0) {
            ull dead = dead8[0];
#pragma unroll
            for (int w2 = 1; w2 < NWAVE; ++w2) dead |= dead8[w2];
            ull alive = ~dead;
            int m = 0;
            const int maxm = MAX_INST - count;
            while (alive && m < maxm) {
                int i = __builtin_ctzll(alive);
                float4 kb;
                kb.x = __shfl(bj.x, i);
                kb.y = __shfl(bj.y, i);
                kb.z = __shfl(bj.z, i);
                kb.w = __shfl(bj.w, i);
                float ks = __shfl(sj, i);
                if (lane == 0) {
                    s_keptbox[count + m]   = kb;
                    s_keptscore[count + m] = ks;
                }
                ++m;
                ull sup = __ballot(iou_pair(kb, bj) > NMS_THR);
                alive &= ~sup;
                alive &= ~(1ull << i);
            }
            if (lane == 0) s_m = m;
        }
        __syncthreads();
        count += s_m;
    }

    // ---- Epilogue: write all MAX_INST rows (kept values, zeros elsewhere) ----
    for (int i = tid; i < MAX_INST * 5; i += BLOCK) {
        int r = i / 5, c = i % 5;
        float vout = 0.0f;
        if (r < count) {
            float4 bb = s_keptbox[r];
            vout = (c == 0) ? bb.x
                 : (c == 1) ? bb.y
                 : (c == 2) ? bb.z
                 : (c == 3) ? bb.w
                 :            s_keptscore[r];
        }
        outb[i] = vout;
    }
}

extern "C" void kernel_launch(void* const* d_in, const int* in_sizes, int n_in,
                              void* d_out, int out_size, void* d_ws, size_t ws_size,
                              hipStream_t stream) {
    const float* rois    = (const float*)d_in[0];
    const float* scores  = (const float*)d_in[1];
    const float* deltas  = (const float*)d_in[2];
    const float* window  = (const float*)d_in[3];
    float* out = (float*)d_out;
    detect_refine_kernel<<<NBATCH, BLOCK, 0, stream>>>(rois, scores, deltas, window, out);
}